// Round 1
// baseline (240.679 us; speedup 1.0000x reference)
//
#include <hip/hip_runtime.h>
#include <math.h>

// HR_HLIFLayer2D: leaky integrate-and-fire over T=32 timesteps.
// x: (B=16, T=32, C=64, H=32, W=32) f32; vth_raw/decay_raw: (C,H,W) f32.
// out: spikes (B,T,C,H,W) f32 in {0.0, 1.0}.
//
// Parallel over (B, CHW); sequential over T in registers. One thread owns
// 4 consecutive CHW elements (float4 loads/stores, coalesced across lanes).
//
// Numerics: recurrence uses explicit __fmul_rn/__fadd_rn/__fsub_rn to match
// the fp32 reference op order exactly (no FMA contraction). Params computed
// with double transcendentals, rounded once to fp32 per reference op sequence.

#define LIF_B   16
#define LIF_T   32
#define LIF_CHW 65536   // 64*32*32
#define LIF_CHW4 16384  // CHW / 4

__global__ __launch_bounds__(256) void HR_HLIFLayer2D_kernel(
    const float* __restrict__ x,
    const float* __restrict__ vth_raw,
    const float* __restrict__ decay_raw,
    float* __restrict__ out)
{
    const int g = blockIdx.x * 256 + threadIdx.x;   // [0, B*CHW4)
    const int b = g >> 14;                          // g / CHW4
    const int j = g & (LIF_CHW4 - 1);               // float4 index within CHW

    const float4 vr4 = reinterpret_cast<const float4*>(vth_raw)[j];
    const float4 dr4 = reinterpret_cast<const float4*>(decay_raw)[j];
    const float vrr[4] = {vr4.x, vr4.y, vr4.z, vr4.w};
    const float drr[4] = {dr4.x, dr4.y, dr4.z, dr4.w};

    float vth[4], dec[4];
#pragma unroll
    for (int i = 0; i < 4; ++i) {
        // vth = softplus(vth_raw*0.1 + 0.5) + 0.01, fp32 rounding sequence
        float a  = __fmul_rn(vrr[i], 0.1f);
        float bb = __fadd_rn(a, 0.5f);
        double sp = log1p(exp((double)bb));          // correctly-rounded softplus
        vth[i] = __fadd_rn((float)sp, 0.01f);

        // decay = clip(sigmoid(decay_raw*0.1 + 2.0), 0, 0.99)
        float z = __fmul_rn(drr[i], 0.1f);
        float w = __fadd_rn(z, 2.0f);
        double sg = 1.0 / (1.0 + exp(-(double)w));
        float sgf = (float)sg;
        sgf = fminf(fmaxf(sgf, 0.0f), 0.99f);        // never binds in practice
        dec[i] = sgf;
    }

    float v[4] = {0.f, 0.f, 0.f, 0.f};
    const size_t base4 = (size_t)b * (LIF_T * LIF_CHW4) + (size_t)j;
    const float4* __restrict__ x4 = reinterpret_cast<const float4*>(x);
    float4* __restrict__ o4 = reinterpret_cast<float4*>(out);

#pragma unroll
    for (int t = 0; t < LIF_T; ++t) {
        const size_t idx = base4 + (size_t)t * LIF_CHW4;
        const float4 xt = x4[idx];
        const float xi[4] = {xt.x, xt.y, xt.z, xt.w};
        float s[4];
#pragma unroll
        for (int i = 0; i < 4; ++i) {
            // v = v*decay + x_t   (separate mul, add — match ref rounding)
            float vv = __fadd_rn(__fmul_rn(v[i], dec[i]), xi[i]);
            // s = (v - vth > 0) ? 1 : 0
            float d = __fsub_rn(vv, vth[i]);
            bool fire = (d > 0.0f);
            s[i] = fire ? 1.0f : 0.0f;
            // v = v - s*vth: s=1 -> exactly d (fl(v - vth)); s=0 -> exactly vv
            v[i] = fire ? d : vv;
        }
        o4[idx] = make_float4(s[0], s[1], s[2], s[3]);
    }
}

extern "C" void kernel_launch(void* const* d_in, const int* in_sizes, int n_in,
                              void* d_out, int out_size, void* d_ws, size_t ws_size,
                              hipStream_t stream) {
    const float* x         = (const float*)d_in[0];
    const float* vth_raw   = (const float*)d_in[1];
    const float* decay_raw = (const float*)d_in[2];
    float* out             = (float*)d_out;

    const int total_threads = LIF_B * LIF_CHW4;   // 262144
    const int block = 256;
    const int grid = total_threads / block;       // 1024
    HR_HLIFLayer2D_kernel<<<grid, block, 0, stream>>>(x, vth_raw, decay_raw, out);
}

// Round 2
// 232.711 us; speedup vs baseline: 1.0342x; 1.0342x over previous
//
#include <hip/hip_runtime.h>
#include <math.h>

// HR_HLIFLayer2D: leaky integrate-and-fire over T=32 timesteps.
// x: (B=16, T=32, C=64, H=32, W=32) f32; vth_raw/decay_raw: (C,H,W) f32.
// out: spikes (B,T,C,H,W) f32 in {0.0, 1.0}.
//
// R2: 2 elements/thread (float2) -> 2048 blocks = 32 waves/CU (full occupancy),
// explicit depth-2 prefetch of x_{t+1}, non-temporal stores for spikes (output
// is write-once; avoid evicting the L3-resident portion of x).
//
// Numerics: recurrence uses explicit __fmul_rn/__fadd_rn/__fsub_rn to match
// the fp32 reference op order exactly (no FMA contraction). Params computed
// with double transcendentals, rounded once to fp32 per reference op sequence.

#define LIF_B    16
#define LIF_T    32
#define LIF_CHW  65536   // 64*32*32
#define LIF_CHW2 32768   // CHW / 2

typedef float vf2 __attribute__((ext_vector_type(2)));

__global__ __launch_bounds__(256) void HR_HLIFLayer2D_kernel(
    const float* __restrict__ x,
    const float* __restrict__ vth_raw,
    const float* __restrict__ decay_raw,
    float* __restrict__ out)
{
    const int g = blockIdx.x * 256 + threadIdx.x;   // [0, B*CHW2)
    const int b = g >> 15;                          // g / CHW2
    const int j = g & (LIF_CHW2 - 1);               // float2 index within CHW

    const vf2 vr2 = reinterpret_cast<const vf2*>(vth_raw)[j];
    const vf2 dr2 = reinterpret_cast<const vf2*>(decay_raw)[j];
    const float vrr[2] = {vr2.x, vr2.y};
    const float drr[2] = {dr2.x, dr2.y};

    float vth[2], dec[2];
#pragma unroll
    for (int i = 0; i < 2; ++i) {
        // vth = softplus(vth_raw*0.1 + 0.5) + 0.01, fp32 rounding sequence
        float a  = __fmul_rn(vrr[i], 0.1f);
        float bb = __fadd_rn(a, 0.5f);
        double sp = log1p(exp((double)bb));          // correctly-rounded softplus
        vth[i] = __fadd_rn((float)sp, 0.01f);

        // decay = clip(sigmoid(decay_raw*0.1 + 2.0), 0, 0.99)
        float z = __fmul_rn(drr[i], 0.1f);
        float w = __fadd_rn(z, 2.0f);
        double sg = 1.0 / (1.0 + exp(-(double)w));
        float sgf = (float)sg;
        sgf = fminf(fmaxf(sgf, 0.0f), 0.99f);        // never binds in practice
        dec[i] = sgf;
    }

    float v[2] = {0.f, 0.f};
    const size_t base2 = (size_t)b * (LIF_T * LIF_CHW2) + (size_t)j;
    const vf2* __restrict__ x2 = reinterpret_cast<const vf2*>(x);
    vf2* __restrict__ o2 = reinterpret_cast<vf2*>(out);

    // depth-2 software pipeline: xt holds x_t, prefetch x_{t+1} before compute
    vf2 xt = x2[base2];
#pragma unroll
    for (int t = 0; t < LIF_T; ++t) {
        const size_t idx = base2 + (size_t)t * LIF_CHW2;
        vf2 xn;
        if (t + 1 < LIF_T) xn = x2[idx + LIF_CHW2];   // compile-time branch (full unroll)

        const float xi[2] = {xt.x, xt.y};
        vf2 s;
        float so[2];
#pragma unroll
        for (int i = 0; i < 2; ++i) {
            // v = v*decay + x_t   (separate mul, add — match ref rounding)
            float vv = __fadd_rn(__fmul_rn(v[i], dec[i]), xi[i]);
            // s = (v - vth > 0) ? 1 : 0
            float d = __fsub_rn(vv, vth[i]);
            bool fire = (d > 0.0f);
            so[i] = fire ? 1.0f : 0.0f;
            // v = v - s*vth: s=1 -> exactly d (fl(v - vth)); s=0 -> exactly vv
            v[i] = fire ? d : vv;
        }
        s.x = so[0]; s.y = so[1];
        __builtin_nontemporal_store(s, &o2[idx]);     // spikes never re-read
        xt = xn;
    }
}

extern "C" void kernel_launch(void* const* d_in, const int* in_sizes, int n_in,
                              void* d_out, int out_size, void* d_ws, size_t ws_size,
                              hipStream_t stream) {
    const float* x         = (const float*)d_in[0];
    const float* vth_raw   = (const float*)d_in[1];
    const float* decay_raw = (const float*)d_in[2];
    float* out             = (float*)d_out;

    const int total_threads = LIF_B * LIF_CHW2;   // 524288
    const int block = 256;
    const int grid = total_threads / block;       // 2048 blocks = 8 blocks/CU
    HR_HLIFLayer2D_kernel<<<grid, block, 0, stream>>>(x, vth_raw, decay_raw, out);
}